// Round 12
// baseline (1334.096 us; speedup 1.0000x reference)
//
#include <hip/hip_runtime.h>

// MoE FFN top-2/8. R12: final = R4 lineage (proven 903us m97-regime loop,
// 128x128 tiles, 4 waves, single-buffer 32KB LDS, compacted tile grid,
// pre-swizzled-source LDS) + three locality/balance tweaks to down:
// (1) grid transposed so the 16 blocks sharing an H row-slab co-schedule
// (L2 reuse of the 8x H re-read), (2) K-split=2 (tail removal, 2048 blocks
// = 2 exact capacity rounds), (3) launch_bounds(256,5) for a 5th resident
// block/CU (32KB x 5 = 160KB LDS). Numerics identical to R4.

#define DM 1024
#define DI 4096
#define NE 8
#define TOK 8192
#define MAXPE 8192
#define BM 128
#define BK 64
#define NTILES 136           // >= sum ceil(ne/128) = 135 worst case

typedef __attribute__((ext_vector_type(4))) float f32x4;
typedef __attribute__((ext_vector_type(8))) short bf16x8;
typedef __attribute__((ext_vector_type(8))) unsigned short u16x8;

#define MFMA(a, b, c) __builtin_amdgcn_mfma_f32_16x16x32_bf16(a, b, c, 0, 0, 0)
#define GLDS16(g, l) __builtin_amdgcn_global_load_lds( \
    (const __attribute__((address_space(1))) unsigned int*)(g), \
    (__attribute__((address_space(3))) unsigned int*)(l), 16, 0, 0)

__device__ __forceinline__ unsigned short bf16_rn(float f) {
    unsigned int u = __builtin_bit_cast(unsigned int, f);
    u += 0x7fffu + ((u >> 16) & 1u);
    return (unsigned short)(u >> 16);
}

// ---------------------------------------------------------------------------
// Router (numerics frozen since R1).
// ---------------------------------------------------------------------------
__global__ __launch_bounds__(256) void router_kernel(
    const float* __restrict__ x, const float* __restrict__ rw,
    const float* __restrict__ rb,
    int* __restrict__ counts, int* __restrict__ tok_list,
    float* __restrict__ w_list)
{
    int t = blockIdx.x * 4 + (threadIdx.x >> 6);
    int lane = threadIdx.x & 63;
    const float* xr = x + (size_t)t * DM;
    float acc[NE];
#pragma unroll
    for (int e = 0; e < NE; ++e) acc[e] = 0.f;
    for (int i = lane; i < DM; i += 64) {
        float xv = xr[i];
#pragma unroll
        for (int e = 0; e < NE; ++e) acc[e] += xv * rw[e * DM + i];
    }
#pragma unroll
    for (int e = 0; e < NE; ++e) {
        float v = acc[e];
#pragma unroll
        for (int s = 32; s >= 1; s >>= 1) v += __shfl_xor(v, s, 64);
        acc[e] = v;
    }
    if (lane == 0) {
        float l0 = -3.4e38f, l1 = -3.4e38f;
        int i0 = 0, i1 = 0;
#pragma unroll
        for (int e = 0; e < NE; ++e) {
            float v = acc[e] + rb[e];
            if (v > l0) { l1 = l0; i1 = i0; l0 = v; i0 = e; }
            else if (v > l1) { l1 = v; i1 = e; }
        }
        float z = expf(l1 - l0);
        float w0 = 1.f / (1.f + z);
        float w1 = z / (1.f + z);
        int p0 = atomicAdd(&counts[i0], 1);
        tok_list[i0 * MAXPE + p0] = t; w_list[i0 * MAXPE + p0] = w0;
        int p1 = atomicAdd(&counts[i1], 1);
        tok_list[i1 * MAXPE + p1] = t; w_list[i1 * MAXPE + p1] = w1;
    }
}

// Prefix offsets + compact (expert, mb) tile table. Sentinel -1 pads.
__global__ void scan_kernel(const int* __restrict__ counts,
                            int* __restrict__ offs, int* __restrict__ tiles) {
    if (threadIdx.x == 0) {
        int s = 0, nt = 0;
        for (int e = 0; e < NE; ++e) { offs[e] = s; s += counts[e]; }
        for (int e = 0; e < NE; ++e) {
            int nmb = (counts[e] + BM - 1) / BM;
            for (int mb = 0; mb < nmb && nt < NTILES; ++mb)
                tiles[nt++] = (e << 16) | mb;
        }
        for (; nt < NTILES; ++nt) tiles[nt] = -1;
    }
}

// ---------------------------------------------------------------------------
// f32 -> bf16 conversion, 8 elems/thread, optional per-expert source stride.
// ---------------------------------------------------------------------------
__global__ __launch_bounds__(256) void conv_kernel(
    const float* __restrict__ src, unsigned short* __restrict__ dst,
    long total, int shift, long estride)
{
    long i8 = ((long)blockIdx.x * 256 + threadIdx.x) * 8;
    if (i8 >= total) return;
    long e = i8 >> shift;
    long r = i8 - (e << shift);
    const float* s = src + e * estride + r;
    f32x4 a = *(const f32x4*)s;
    f32x4 b = *(const f32x4*)(s + 4);
    u16x8 o;
#pragma unroll
    for (int j = 0; j < 4; ++j) { o[j] = bf16_rn(a[j]); o[4 + j] = bf16_rn(b[j]); }
    *(u16x8*)(dst + i8) = o;
}

// ---------------------------------------------------------------------------
// Gate+Up GEMM: 128 tokens x (64 gate + 64 up cols), BK=64, 4 waves,
// single-buffer 32KB LDS (m97 structure), pre-swizzled source columns.
// (Byte-identical to R4's gateup3 except launch_bounds 4 -> 5.)
// ---------------------------------------------------------------------------
__global__ __launch_bounds__(256, 5) void gateup3(
    const unsigned short* __restrict__ xb,
    const unsigned short* __restrict__ gwb,   // [NE][CHC][DM] slice
    const unsigned short* __restrict__ uwb,
    const int* __restrict__ counts, const int* __restrict__ offs,
    const int* __restrict__ tiles, const int* __restrict__ tok_list,
    unsigned short* __restrict__ H, int cb, int CHC)
{
    const int pk = tiles[blockIdx.x];
    if (pk < 0) return;
    const int e = pk >> 16, mb = pk & 0xffff;
    const int ne = counts[e];
    const int by = blockIdx.y;
    const int tid = threadIdx.x;
    const int lane = tid & 63, w = tid >> 6;
    const int lr = lane & 15, lk = lane >> 4;
    const int lrow = lane >> 3;                       // lds row within 8-row group
    const int lcol = (((lane & 7) ^ lrow) << 3);      // pre-swizzled source col

    __shared__ __align__(16) unsigned short As[BM * BK];   // 16KB
    __shared__ __align__(16) unsigned short Bg[64 * BK];   // 8KB
    __shared__ __align__(16) unsigned short Bu[64 * BK];   // 8KB

    size_t srcA[4];
#pragma unroll
    for (int i = 0; i < 4; ++i) {
        int rg = mb * BM + w * 32 + i * 8 + lrow;
        int rc = rg < ne ? rg : ne - 1;               // clamp tail -> finite data
        int tok = tok_list[e * MAXPE + rc];
        srcA[i] = (size_t)tok * DM + lcol;
    }
    size_t srcB[2];
#pragma unroll
    for (int i = 0; i < 2; ++i) {
        int row = by * 64 + w * 16 + i * 8 + lrow;
        srcB[i] = ((size_t)e * CHC + row) * DM + lcol;
    }

    const int wm = w >> 1, wn = w & 1;
    const int xsw = (lr & 7) << 4;                    // read-side XOR (bytes)
    f32x4 accg[4][2], accu[4][2];
#pragma unroll
    for (int m = 0; m < 4; ++m)
#pragma unroll
        for (int n = 0; n < 2; ++n) { accg[m][n] = (f32x4)0.f; accu[m][n] = (f32x4)0.f; }

    for (int kt = 0; kt < DM / BK; ++kt) {
        const int kb = kt * BK;
#pragma unroll
        for (int i = 0; i < 4; ++i)
            GLDS16(xb + srcA[i] + kb, &As[(w * 32 + i * 8) * BK]);
#pragma unroll
        for (int i = 0; i < 2; ++i) {
            GLDS16(gwb + srcB[i] + kb, &Bg[(w * 16 + i * 8) * BK]);
            GLDS16(uwb + srcB[i] + kb, &Bu[(w * 16 + i * 8) * BK]);
        }
        __syncthreads();
#pragma unroll
        for (int ks = 0; ks < 2; ++ks) {
            const int kbyte = (ks * 64 + lk * 16) ^ xsw;
            bf16x8 a[4], bg[2], bu[2];
#pragma unroll
            for (int mf = 0; mf < 4; ++mf)
                a[mf] = *(const bf16x8*)((const char*)As +
                         (wm * 64 + mf * 16 + lr) * 128 + kbyte);
#pragma unroll
            for (int nf = 0; nf < 2; ++nf) {
                bg[nf] = *(const bf16x8*)((const char*)Bg +
                          (wn * 32 + nf * 16 + lr) * 128 + kbyte);
                bu[nf] = *(const bf16x8*)((const char*)Bu +
                          (wn * 32 + nf * 16 + lr) * 128 + kbyte);
            }
#pragma unroll
            for (int mf = 0; mf < 4; ++mf)
#pragma unroll
                for (int nf = 0; nf < 2; ++nf) {
                    accg[mf][nf] = MFMA(a[mf], bg[nf], accg[mf][nf]);
                    accu[mf][nf] = MFMA(a[mf], bu[nf], accu[mf][nf]);
                }
        }
        __syncthreads();
    }

    const int hrow0 = offs[e] + mb * BM;
#pragma unroll
    for (int mf = 0; mf < 4; ++mf)
#pragma unroll
        for (int nf = 0; nf < 2; ++nf)
#pragma unroll
            for (int j = 0; j < 4; ++j) {
                int r = wm * 64 + mf * 16 + lk * 4 + j;
                if (mb * BM + r < ne) {
                    int c = cb + by * 64 + wn * 32 + nf * 16 + lr;
                    float g = accg[mf][nf][j], u = accu[mf][nf][j];
                    float h = (g / (1.f + expf(-g))) * u;
                    H[(size_t)(hrow0 + r) * DI + c] = bf16_rn(h);
                }
            }
}

// ---------------------------------------------------------------------------
// Down GEMM: 128 H-rows x 128 out-cols, K-split=2 (K=2048 each), 4 waves,
// single-buffer 32KB LDS. Grid: x = (by,kq) [16], y = tile -> the 16 blocks
// sharing one H row-slab co-schedule (L2 reuse of the 8x re-read).
// ---------------------------------------------------------------------------
__global__ __launch_bounds__(256, 5) void down4(
    const unsigned short* __restrict__ dwb,   // [NE][DM][DI] bf16
    const int* __restrict__ counts, const int* __restrict__ offs,
    const int* __restrict__ tiles, const int* __restrict__ tok_list,
    const float* __restrict__ w_list,
    const unsigned short* __restrict__ H,
    float* __restrict__ out)
{
    const int pk = tiles[blockIdx.y];
    if (pk < 0) return;
    const int e = pk >> 16, mb = pk & 0xffff;
    const int ne = counts[e];
    const int by = blockIdx.x >> 1;           // 0..7 (128-col group of DM)
    const int kq = blockIdx.x & 1;            // K-split half
    const int kbase = kq * (DI / 2);
    const int tid = threadIdx.x;
    const int lane = tid & 63, w = tid >> 6;
    const int lr = lane & 15, lk = lane >> 4;
    const int lrow = lane >> 3;
    const int lcol = (((lane & 7) ^ lrow) << 3);

    __shared__ __align__(16) unsigned short As[BM * BK];    // 16KB
    __shared__ __align__(16) unsigned short Bs[BM * BK];    // 16KB

    const int hrow0 = offs[e] + mb * BM;
    size_t srcA[4], srcB[4];
#pragma unroll
    for (int i = 0; i < 4; ++i) {
        srcA[i] = (size_t)(hrow0 + w * 32 + i * 8 + lrow) * DI + kbase + lcol;
        srcB[i] = ((size_t)e * DM + by * 128 + w * 32 + i * 8 + lrow) * DI + kbase + lcol;
    }

    const int wm = w >> 1, wn = w & 1;
    const int xsw = (lr & 7) << 4;
    f32x4 acc[4][4];
#pragma unroll
    for (int m = 0; m < 4; ++m)
#pragma unroll
        for (int n = 0; n < 4; ++n) acc[m][n] = (f32x4)0.f;

    for (int kt = 0; kt < (DI / 2) / BK; ++kt) {
        const int kb = kt * BK;
#pragma unroll
        for (int i = 0; i < 4; ++i) {
            GLDS16(H + srcA[i] + kb, &As[(w * 32 + i * 8) * BK]);
            GLDS16(dwb + srcB[i] + kb, &Bs[(w * 32 + i * 8) * BK]);
        }
        __syncthreads();
#pragma unroll
        for (int ks = 0; ks < 2; ++ks) {
            const int kbyte = (ks * 64 + lk * 16) ^ xsw;
            bf16x8 a[4], b[4];
#pragma unroll
            for (int mf = 0; mf < 4; ++mf)
                a[mf] = *(const bf16x8*)((const char*)As +
                         (wm * 64 + mf * 16 + lr) * 128 + kbyte);
#pragma unroll
            for (int nf = 0; nf < 4; ++nf)
                b[nf] = *(const bf16x8*)((const char*)Bs +
                         (wn * 64 + nf * 16 + lr) * 128 + kbyte);
#pragma unroll
            for (int mf = 0; mf < 4; ++mf)
#pragma unroll
                for (int nf = 0; nf < 4; ++nf)
                    acc[mf][nf] = MFMA(a[mf], b[nf], acc[mf][nf]);
        }
        __syncthreads();
    }

#pragma unroll
    for (int mf = 0; mf < 4; ++mf)
#pragma unroll
        for (int j = 0; j < 4; ++j) {
            int r = wm * 64 + mf * 16 + lk * 4 + j;
            int row = mb * BM + r;
            if (row < ne) {
                int t = tok_list[e * MAXPE + row];
                float wgt = w_list[e * MAXPE + row];
#pragma unroll
                for (int nf = 0; nf < 4; ++nf) {
                    int c = by * 128 + wn * 64 + nf * 16 + lr;
                    atomicAdd(&out[(size_t)t * DM + c], wgt * acc[mf][nf][j]);
                }
            }
        }
}

// ---------------------------------------------------------------------------
extern "C" void kernel_launch(void* const* d_in, const int* in_sizes, int n_in,
                              void* d_out, int out_size, void* d_ws, size_t ws_size,
                              hipStream_t stream) {
    const float* x = (const float*)d_in[0];
    const float* router_w = (const float*)d_in[1];
    const float* router_b = (const float*)d_in[2];
    const float* gate_w = (const float*)d_in[3];
    const float* up_w = (const float*)d_in[4];
    const float* down_w = (const float*)d_in[5];
    float* out = (float*)d_out;

    char* ws = (char*)d_ws;
    int* counts = (int*)ws;                              // +0
    int* offs = (int*)(ws + 64);                         // +64
    int* tiles = (int*)(ws + 128);                       // +128 (136 ints)
    int* tok_list = (int*)(ws + 768);
    float* w_list = (float*)(ws + 768 + (size_t)NE * MAXPE * 4);
    size_t off = 768 + (size_t)NE * MAXPE * 8;
    off = (off + 255) & ~(size_t)255;

    unsigned short* xb = (unsigned short*)(ws + off);  off += (size_t)TOK * DM * 2;
    unsigned short* dwb = (unsigned short*)(ws + off); off += (size_t)NE * DM * DI * 2;
    unsigned short* H = (unsigned short*)(ws + off);   off += (size_t)(2 * TOK + BM) * DI * 2;

    int CHC = 64;
    for (int c = 2048; c >= 64; c >>= 1)
        if (off + (size_t)2 * NE * c * DM * 2 <= ws_size) { CHC = c; break; }
    unsigned short* gwb = (unsigned short*)(ws + off);
    unsigned short* uwb = gwb + (size_t)NE * CHC * DM;

    hipMemsetAsync(out, 0, (size_t)out_size * sizeof(float), stream);
    hipMemsetAsync(counts, 0, NE * sizeof(int), stream);

    router_kernel<<<TOK / 4, 256, 0, stream>>>(x, router_w, router_b,
                                               counts, tok_list, w_list);
    scan_kernel<<<1, 64, 0, stream>>>(counts, offs, tiles);

    conv_kernel<<<(TOK * DM) / 2048, 256, 0, stream>>>(
        x, xb, (long)TOK * DM, 23, 0);
    conv_kernel<<<(int)(((long)NE * DM * DI) / 2048), 256, 0, stream>>>(
        down_w, dwb, (long)NE * DM * DI, 25, 0);

    const int sh = 10 + __builtin_ctz((unsigned)CHC);   // log2(CHC*DM)
    for (int cb = 0; cb < DI; cb += CHC) {
        long tot = (long)NE * CHC * DM;
        conv_kernel<<<(int)(tot / 2048), 256, 0, stream>>>(
            gate_w + (size_t)cb * DM, gwb, tot, sh, (long)DI * DM);
        conv_kernel<<<(int)(tot / 2048), 256, 0, stream>>>(
            up_w + (size_t)cb * DM, uwb, tot, sh, (long)DI * DM);
        gateup3<<<dim3(NTILES, CHC / 64), 256, 0, stream>>>(
            xb, gwb, uwb, counts, offs, tiles, tok_list, H, cb, CHC);
    }
    down4<<<dim3(16, NTILES), 256, 0, stream>>>(
        dwb, counts, offs, tiles, tok_list, w_list, H, out);
}